// Round 1
// 1576.166 us; speedup vs baseline: 1.8232x; 1.8232x over previous
//
#include <hip/hip_runtime.h>
#include <stdint.h>

// Problem constants
#define BB     64
#define NPTS   1024
#define DIM    256
#define BOOKN  2048
#define NC     16
#define NROWS  (BB*NPTS)           // 65536
#define HALF_N 67108864u           // NROWS*BOOKN/2
#define HALF_ROWS 32768            // NROWS/2

// d_out layout (floats): [zq | precision_q | logits | mu_mix]
#define OFF_PQ ((size_t)NROWS*DIM)            // 16777216
#define OFF_LG (OFF_PQ + 1)                   // 16777217
#define OFF_MM (OFF_LG + (size_t)NROWS*BOOKN) // 150994945

// ws layout (floats): bn[2048], rn[65536], pq[1], pad, bookF (2048*256 bf16 = 1MB)
// total ~1.32 MB
#define WS_RN 2048
#define WS_PQ (2048 + NROWS)
#define WS_BF 67592                // float offset, 16B aligned

typedef unsigned short u16;
typedef short s8v  __attribute__((ext_vector_type(8)));   // 8 bf16 = 4 VGPR (MFMA A/B frag)
typedef float f32x4 __attribute__((ext_vector_type(4)));  // MFMA C/D frag
typedef u16  u16x4 __attribute__((ext_vector_type(4)));
typedef u16  u16x8 __attribute__((ext_vector_type(8)));

__device__ __forceinline__ u16 f2bf(float x){
  uint32_t u = __float_as_uint(x);
  return (u16)((u + 0x7fffu + ((u >> 16) & 1u)) >> 16);   // RNE
}
__device__ __forceinline__ float bf2f(u16 b){
  return __uint_as_float(((uint32_t)b) << 16);
}

// ---------------- threefry2x32-20, JAX semantics, key = (0, 42) -------------
__device__ __forceinline__ uint32_t rotl32(uint32_t x, int r){
  return (x << r) | (x >> (32 - r));
}

__device__ __forceinline__ void threefry_0_42(uint32_t x0, uint32_t x1,
                                              uint32_t& o0, uint32_t& o1){
  const uint32_t ks0 = 0u;
  const uint32_t ks1 = 42u;
  const uint32_t ks2 = 0u ^ 42u ^ 0x1BD11BDAu;
  x0 += ks0; x1 += ks1;
#define TF_R(r) { x0 += x1; x1 = rotl32(x1, r); x1 ^= x0; }
  TF_R(13) TF_R(15) TF_R(26) TF_R(6)
  x0 += ks1; x1 += ks2 + 1u;
  TF_R(17) TF_R(29) TF_R(16) TF_R(24)
  x0 += ks2; x1 += ks0 + 2u;
  TF_R(13) TF_R(15) TF_R(26) TF_R(6)
  x0 += ks0; x1 += ks1 + 3u;
  TF_R(17) TF_R(29) TF_R(16) TF_R(24)
  x0 += ks1; x1 += ks2 + 4u;
  TF_R(13) TF_R(15) TF_R(26) TF_R(6)
  x0 += ks2; x1 += ks0 + 5u;
#undef TF_R
  o0 = x0; o1 = x1;
}

__device__ __forceinline__ float gumbel_from_bits(uint32_t bits){
  // jax uniform: bitcast((bits>>9)|0x3f800000) - 1.0  in [0,1)
  float u = __uint_as_float((bits >> 9) | 0x3f800000u) - 1.0f;
  return -logf(-logf(u + 1e-10f) + 1e-10f);
}

// ---------------- K0: book norms + precision_q ------------------------------
__global__ __launch_bounds__(256) void k_prep(const float* __restrict__ book,
    const float* __restrict__ lpq, float* __restrict__ bn,
    float* __restrict__ ws_pq, float* __restrict__ pq_out)
{
  __shared__ float red[4];
  const int j = blockIdx.x, t = threadIdx.x;
  float v = book[(size_t)j*DIM + t];
  float s = v*v;
  #pragma unroll
  for (int o = 32; o; o >>= 1) s += __shfl_down(s, o, 64);
  const int wv = t >> 6, ln = t & 63;
  if (ln == 0) red[wv] = s;
  __syncthreads();
  if (t == 0){
    bn[j] = red[0] + red[1] + red[2] + red[3];
    if (j == 0){
      float pq = fmaxf(expf(lpq[0]), 1e-10f);
      float prec = 0.5f / pq;
      ws_pq[0] = prec;
      pq_out[0] = prec;
    }
  }
}

// ---------------- K0b: fragment-ordered bf16 book for k_zq B operand --------
// bookF frag (jc, dt, lane): element e = book[jc*32 + (lane>>4)*8 + e][dt*16 + (lane&15)]
// flat: bookF[ ((jc*16 + dt)*64 + lane)*8 + e ]
__global__ __launch_bounds__(256) void k_bookf(const float* __restrict__ book,
                                               u16* __restrict__ bookF)
{
  const int tid = blockIdx.x*256 + threadIdx.x;   // 0..65535 = (jc*16+dt)*64+lane
  const int l  = tid & 63;
  const int dt = (tid >> 6) & 15;
  const int jc = tid >> 10;
  const int d  = dt*16 + (l & 15);
  const int jb = jc*32 + (l >> 4)*8;
  u16x8 v;
  #pragma unroll
  for (int e = 0; e < 8; ++e) v[e] = f2bf(book[(size_t)(jb + e)*DIM + d]);
  *(u16x8*)&bookF[(size_t)tid*8] = v;
}

// ---------------- K1: mu_mix, zp (into zq slot), row norms ------------------
__global__ __launch_bounds__(256) void k_mix(const float* __restrict__ z,
    const float* __restrict__ cp, const float* __restrict__ mu,
    float* __restrict__ zp, float* __restrict__ mm, float* __restrict__ rn)
{
  __shared__ float s_cp[BB*NC];   // 1024
  __shared__ float s_red[4];
  const int n = blockIdx.x;
  const int t = threadIdx.x;      // = d
  for (int e = t; e < BB*NC; e += 256) s_cp[e] = cp[e];
  float muv[NC];
  #pragma unroll
  for (int c = 0; c < NC; ++c) muv[c] = mu[(size_t)(c*NPTS + n)*DIM + t];
  __syncthreads();
  const int wv = t >> 6, ln = t & 63;
  for (int b = 0; b < BB; ++b){
    float m = 0.f;
    #pragma unroll
    for (int c = 0; c < NC; ++c) m = fmaf(s_cp[b*NC + c], muv[c], m);
    const size_t idx = ((size_t)(b*NPTS + n))*DIM + t;
    const float zpv = z[idx] + m;
    mm[idx] = m;
    zp[idx] = zpv;
    float s = zpv*zpv;
    #pragma unroll
    for (int o = 32; o; o >>= 1) s += __shfl_down(s, o, 64);
    if (ln == 0) s_red[wv] = s;
    __syncthreads();
    if (t == 0) rn[b*NPTS + n] = s_red[0] + s_red[1] + s_red[2] + s_red[3];
    __syncthreads();
  }
}

// ---------------- K2: logits GEMM via bf16 MFMA -----------------------------
// 128x128 tile, 4 waves 2x2, each wave 64x64 (4x4 tiles of 16x16), K chunks of 64.
// LDS row pitch 72 bf16 = 144 B (16B-aligned, 2-way banks on frag reads = free).
// logits = -pq*(rn[i] + bn[j] - 2*dot_bf16(zp_i, book_j)); norms stay exact f32.
__global__ __launch_bounds__(256) void k_logits(const float* __restrict__ zp,
    const float* __restrict__ book, const float* __restrict__ rn,
    const float* __restrict__ bn, const float* __restrict__ ws_pq,
    float* __restrict__ logits)
{
  __shared__ u16 sA[128*72];
  __shared__ u16 sB[128*72];
  const int t  = threadIdx.x;
  const int l  = t & 63;
  const int w  = t >> 6;
  const int i0 = blockIdx.y * 128;
  const int j0 = blockIdx.x * 128;
  const int wr = (w >> 1) * 64;
  const int wc = (w & 1) * 64;
  const int ll = l & 15, lh = l >> 4;

  f32x4 acc[4][4];
  #pragma unroll
  for (int m = 0; m < 4; ++m)
    #pragma unroll
    for (int n = 0; n < 4; ++n)
      acc[m][n] = (f32x4){0.f, 0.f, 0.f, 0.f};

  for (int k0 = 0; k0 < DIM; k0 += 64){
    // stage A (zp rows) and B (book rows) as bf16
    #pragma unroll
    for (int e = 0; e < 8; ++e){
      const int idx = e*256 + t;
      const int r  = idx >> 4;          // 0..127
      const int dd = (idx & 15) * 4;    // 0..60
      const float4 a4 = *(const float4*)&zp[(size_t)(i0 + r)*DIM + k0 + dd];
      const float4 b4 = *(const float4*)&book[(size_t)(j0 + r)*DIM + k0 + dd];
      u16x4 av, bv;
      av[0] = f2bf(a4.x); av[1] = f2bf(a4.y); av[2] = f2bf(a4.z); av[3] = f2bf(a4.w);
      bv[0] = f2bf(b4.x); bv[1] = f2bf(b4.y); bv[2] = f2bf(b4.z); bv[3] = f2bf(b4.w);
      *(u16x4*)&sA[r*72 + dd] = av;
      *(u16x4*)&sB[r*72 + dd] = bv;
    }
    __syncthreads();
    #pragma unroll
    for (int kk = 0; kk < 2; ++kk){
      s8v aF[4], bF[4];
      #pragma unroll
      for (int m = 0; m < 4; ++m)
        aF[m] = *(const s8v*)&sA[(wr + m*16 + ll)*72 + kk*32 + lh*8];
      #pragma unroll
      for (int n = 0; n < 4; ++n)
        bF[n] = *(const s8v*)&sB[(wc + n*16 + ll)*72 + kk*32 + lh*8];
      #pragma unroll
      for (int m = 0; m < 4; ++m)
        #pragma unroll
        for (int n = 0; n < 4; ++n)
          acc[m][n] = __builtin_amdgcn_mfma_f32_16x16x32_bf16(aF[m], bF[n], acc[m][n], 0, 0, 0);
    }
    __syncthreads();
  }

  // epilogue: C/D layout col = lane&15, row = (lane>>4)*4 + reg
  const float pq = ws_pq[0];
  float bnv[4];
  #pragma unroll
  for (int n = 0; n < 4; ++n) bnv[n] = bn[j0 + wc + n*16 + ll];
  #pragma unroll
  for (int m = 0; m < 4; ++m){
    #pragma unroll
    for (int r = 0; r < 4; ++r){
      const int i = i0 + wr + m*16 + lh*4 + r;
      const float rni = rn[i];
      const size_t base = (size_t)i*BOOKN + j0 + wc + ll;
      #pragma unroll
      for (int n = 0; n < 4; ++n)
        logits[base + n*16] = -pq * (rni + bnv[n] - 2.0f*acc[m][n][r]);
    }
  }
}

// ---------------- K3: fused gumbel-softmax + zq GEMM via bf16 MFMA ----------
// Block: 32 first-half rows + 32 paired rows (+HALF_ROWS), 4 waves each owning
// a 64-wide d slice. Per 32-col chunk: compute p (f32, exact threefry path),
// round to bf16 into sP (pitch 40 u16 = 80 B, 16B-aligned, 2-way banks), then
// 16 MFMAs/wave with B frags streamed from pre-fragmented bookF (coalesced 16B).
// Normalization uses f32 sum of the *rounded* p (consistent num/denominator).
__global__ __launch_bounds__(256) void k_zq(const float* __restrict__ logits,
    const u16* __restrict__ bookF, const int* __restrict__ temp,
    float* __restrict__ zq)
{
  __shared__ u16 sP[64*40];
  __shared__ float sM[64];
  __shared__ float sS[64][8];
  __shared__ float sInv[64];
  const int t  = threadIdx.x;
  const int i0 = blockIdx.x * 32;
  const float tinv = 1.0f / (float)temp[0];

  // Pass 1: per-row max of logits (+17 covers max gumbel ~16.64)
  {
    const int wv = t >> 6, ln = t & 63;
    for (int rr = 0; rr < 16; ++rr){
      const int r = wv*16 + rr;
      const int gi = (r < 32) ? (i0 + r) : (i0 + r - 32 + HALF_ROWS);
      const float* row = logits + (size_t)gi*BOOKN;
      float mx = -3.4e38f;
      #pragma unroll 4
      for (int e = 0; e < 32; ++e) mx = fmaxf(mx, row[e*64 + ln]);
      #pragma unroll
      for (int o = 32; o; o >>= 1) mx = fmaxf(mx, __shfl_down(mx, o, 64));
      if (ln == 0) sM[r] = mx + 17.0f;
    }
  }
  __syncthreads();

  const int w   = t >> 6;        // wave id: owns d-range w*64 .. +63
  const int l   = t & 63;
  const int ll  = l & 15, lh = l >> 4;
  const int srA = t >> 3;        // staging row 0..31
  const int sj0 = (t & 7) * 4;   // staging col start within chunk
  const int giA = i0 + srA;
  const float mA = sM[srA];
  const float mB = sM[srA + 32];
  const float* rowA = logits + (size_t)giA*BOOKN;
  const float* rowB = logits + (size_t)(giA + HALF_ROWS)*BOOKN;

  f32x4 acc[4][4];
  #pragma unroll
  for (int m = 0; m < 4; ++m)
    #pragma unroll
    for (int n = 0; n < 4; ++n)
      acc[m][n] = (f32x4){0.f, 0.f, 0.f, 0.f};
  float sumA = 0.f, sumB = 0.f;

  for (int jc = 0; jc < 64; ++jc){
    const int jbase = jc*32 + sj0;
    const float4 lA4 = *(const float4*)(rowA + jbase);
    const float4 lB4 = *(const float4*)(rowB + jbase);
    const float la[4] = {lA4.x, lA4.y, lA4.z, lA4.w};
    const float lb[4] = {lB4.x, lB4.y, lB4.z, lB4.w};
    #pragma unroll
    for (int e = 0; e < 4; ++e){
      const uint32_t p = (uint32_t)(giA*BOOKN + jbase + e);   // < HALF_N
      uint32_t o0, o1;
      threefry_0_42(p, p + HALF_N, o0, o1);
      const float gA = gumbel_from_bits(o0);
      const float gB = gumbel_from_bits(o1);
      const u16 pa = f2bf(expf((la[e] + gA - mA)*tinv));
      const u16 pb = f2bf(expf((lb[e] + gB - mB)*tinv));
      sP[srA*40 + sj0 + e]        = pa;
      sP[(srA + 32)*40 + sj0 + e] = pb;
      sumA += bf2f(pa);
      sumB += bf2f(pb);
    }
    // B frags: coalesced 16B/lane from L2-resident bookF (independent of sP)
    s8v bF[4];
    #pragma unroll
    for (int n = 0; n < 4; ++n)
      bF[n] = *(const s8v*)&bookF[((size_t)(jc*16 + w*4 + n)*64 + l)*8];
    __syncthreads();
    s8v aF[4];
    #pragma unroll
    for (int m = 0; m < 4; ++m)
      aF[m] = *(const s8v*)&sP[(m*16 + ll)*40 + lh*8];
    #pragma unroll
    for (int n = 0; n < 4; ++n)
      #pragma unroll
      for (int m = 0; m < 4; ++m)
        acc[m][n] = __builtin_amdgcn_mfma_f32_16x16x32_bf16(aF[m], bF[n], acc[m][n], 0, 0, 0);
    __syncthreads();
  }

  // S reduction (8 partials per row)
  sS[srA][t & 7]      = sumA;
  sS[srA + 32][t & 7] = sumB;
  __syncthreads();
  if (t < 64){
    float s = 0.f;
    #pragma unroll
    for (int e = 0; e < 8; ++e) s += sS[t][e];
    sInv[t] = 1.0f / s;
  }
  __syncthreads();

  // epilogue: zq = acc / S.  C/D: col(d) = lane&15, row = (lane>>4)*4 + reg
  #pragma unroll
  for (int m = 0; m < 4; ++m){
    #pragma unroll
    for (int r = 0; r < 4; ++r){
      const int lr = m*16 + lh*4 + r;
      const int gi = (lr < 32) ? (i0 + lr) : (i0 + lr - 32 + HALF_ROWS);
      const float inv = sInv[lr];
      #pragma unroll
      for (int n = 0; n < 4; ++n)
        zq[(size_t)gi*DIM + w*64 + n*16 + ll] = acc[m][n][r] * inv;
    }
  }
}

// ---------------- launch ----------------------------------------------------
extern "C" void kernel_launch(void* const* d_in, const int* in_sizes, int n_in,
                              void* d_out, int out_size, void* d_ws, size_t ws_size,
                              hipStream_t stream)
{
  (void)in_sizes; (void)n_in; (void)out_size; (void)ws_size;
  const float* z    = (const float*)d_in[0];
  const float* cp   = (const float*)d_in[1];
  const float* lpq  = (const float*)d_in[2];
  const float* book = (const float*)d_in[3];
  const float* mu   = (const float*)d_in[4];
  const int*   temp = (const int*)d_in[5];
  // d_in[6] = is_train, unused by the reference computation

  float* out = (float*)d_out;
  float* zq  = out;             // also used as zp scratch between K1 and K2
  float* pqo = out + OFF_PQ;
  float* lg  = out + OFF_LG;
  float* mm  = out + OFF_MM;

  float* ws    = (float*)d_ws;  // needs ~1.32 MB
  float* bn    = ws;
  float* rn    = ws + WS_RN;
  float* wpq   = ws + WS_PQ;
  u16*   bookF = (u16*)(ws + WS_BF);

  hipLaunchKernelGGL(k_prep,   dim3(BOOKN), dim3(256), 0, stream,
                     book, lpq, bn, wpq, pqo);
  hipLaunchKernelGGL(k_bookf,  dim3(256), dim3(256), 0, stream,
                     book, bookF);
  hipLaunchKernelGGL(k_mix,    dim3(NPTS), dim3(256), 0, stream,
                     z, cp, mu, zq, mm, rn);
  hipLaunchKernelGGL(k_logits, dim3(BOOKN/128, NROWS/128), dim3(256), 0, stream,
                     zq, book, rn, bn, wpq, lg);
  hipLaunchKernelGGL(k_zq,     dim3(HALF_ROWS/32), dim3(256), 0, stream,
                     lg, bookF, temp, zq);
}

// Round 4
// 1291.373 us; speedup vs baseline: 2.2253x; 1.2205x over previous
//
#include <hip/hip_runtime.h>
#include <stdint.h>

// Problem constants
#define BB     64
#define NPTS   1024
#define DIM    256
#define BOOKN  2048
#define NC     16
#define NROWS  (BB*NPTS)           // 65536
#define HALF_N 67108864u           // NROWS*BOOKN/2
#define HALF_ROWS 32768            // NROWS/2

// d_out layout (floats): [zq | precision_q | logits | mu_mix]
#define OFF_PQ ((size_t)NROWS*DIM)            // 16777216
#define OFF_LG (OFF_PQ + 1)                   // 16777217
#define OFF_MM (OFF_LG + (size_t)NROWS*BOOKN) // 150994945

// ws layout (floats): bn[2048], rn[65536], pq[1], pad, bookF(1MB as bf16),
// then OPTIONAL rowmax(65536 u32) if ws_size permits.
#define WS_RN 2048
#define WS_PQ (2048 + NROWS)
#define WS_BF 67592                            // float offset, 16B aligned
#define WS_MX (WS_BF + (BOOKN*DIM)/2)          // 329736 (float offset)
#define WS_FUSED_BYTES ((size_t)(WS_MX + NROWS) * 4)   // 1,581,088

// fast hardware transcendentals (v_log_f32 = log2, v_exp_f32 = exp2), with
// guaranteed-compile libm fallback. NOTE: __log2f/__exp2f collide with glibc
// math.h internal decls — do not use those names.
#if defined(__has_builtin)
# if __has_builtin(__builtin_amdgcn_logf)
#  define FAST_LOG2(x) __builtin_amdgcn_logf(x)
# endif
# if __has_builtin(__builtin_amdgcn_exp2f)
#  define FAST_EXP2(x) __builtin_amdgcn_exp2f(x)
# endif
#endif
#ifndef FAST_LOG2
# define FAST_LOG2(x) log2f(x)
#endif
#ifndef FAST_EXP2
# define FAST_EXP2(x) exp2f(x)
#endif

typedef unsigned short u16;
typedef short s8v  __attribute__((ext_vector_type(8)));   // 8 bf16 = 4 VGPR (MFMA A/B frag)
typedef float f32x4 __attribute__((ext_vector_type(4)));  // MFMA C/D frag
typedef u16  u16x4 __attribute__((ext_vector_type(4)));
typedef u16  u16x8 __attribute__((ext_vector_type(8)));

__device__ __forceinline__ u16 f2bf(float x){
  uint32_t u = __float_as_uint(x);
  return (u16)((u + 0x7fffu + ((u >> 16) & 1u)) >> 16);   // RNE
}
__device__ __forceinline__ float bf2f(u16 b){
  return __uint_as_float(((uint32_t)b) << 16);
}

// monotone float<->uint map (uint compare == float compare), for atomicMax
__device__ __forceinline__ uint32_t mf_map(float f){
  uint32_t b = __float_as_uint(f);
  return (b & 0x80000000u) ? ~b : (b | 0x80000000u);
}
__device__ __forceinline__ float mf_unmap(uint32_t u){
  uint32_t b = (u & 0x80000000u) ? (u ^ 0x80000000u) : ~u;
  return __uint_as_float(b);
}

// ---------------- threefry2x32-20, JAX semantics, key = (0, 42) -------------
__device__ __forceinline__ uint32_t rotl32(uint32_t x, int r){
  return (x << r) | (x >> (32 - r));
}

__device__ __forceinline__ void threefry_0_42(uint32_t x0, uint32_t x1,
                                              uint32_t& o0, uint32_t& o1){
  const uint32_t ks0 = 0u;
  const uint32_t ks1 = 42u;
  const uint32_t ks2 = 0u ^ 42u ^ 0x1BD11BDAu;
  x0 += ks0; x1 += ks1;
#define TF_R(r) { x0 += x1; x1 = rotl32(x1, r); x1 ^= x0; }
  TF_R(13) TF_R(15) TF_R(26) TF_R(6)
  x0 += ks1; x1 += ks2 + 1u;
  TF_R(17) TF_R(29) TF_R(16) TF_R(24)
  x0 += ks2; x1 += ks0 + 2u;
  TF_R(13) TF_R(15) TF_R(26) TF_R(6)
  x0 += ks0; x1 += ks1 + 3u;
  TF_R(17) TF_R(29) TF_R(16) TF_R(24)
  x0 += ks1; x1 += ks2 + 4u;
  TF_R(13) TF_R(15) TF_R(26) TF_R(6)
  x0 += ks2; x1 += ks0 + 5u;
#undef TF_R
  o0 = x0; o1 = x1;
}

// ---------------- K0: book norms + precision_q + rowmax init ----------------
__global__ __launch_bounds__(256) void k_prep(const float* __restrict__ book,
    const float* __restrict__ lpq, float* __restrict__ bn,
    float* __restrict__ ws_pq, float* __restrict__ pq_out,
    unsigned int* __restrict__ wsMax)
{
  __shared__ float red[4];
  const int j = blockIdx.x, t = threadIdx.x;
  const int gid = j*256 + t;
  if (wsMax != nullptr && gid < NROWS) wsMax[gid] = 0u;  // maps below any finite float
  float v = book[(size_t)j*DIM + t];
  float s = v*v;
  #pragma unroll
  for (int o = 32; o; o >>= 1) s += __shfl_down(s, o, 64);
  const int wv = t >> 6, ln = t & 63;
  if (ln == 0) red[wv] = s;
  __syncthreads();
  if (t == 0){
    bn[j] = red[0] + red[1] + red[2] + red[3];
    if (j == 0){
      float pq = fmaxf(expf(lpq[0]), 1e-10f);
      float prec = 0.5f / pq;
      ws_pq[0] = prec;
      pq_out[0] = prec;
    }
  }
}

// ---------------- K0b: fragment-ordered bf16 book for k_zq B operand --------
// bookF frag (jc, dt, lane): element e = book[jc*32 + (lane>>4)*8 + e][dt*16 + (lane&15)]
__global__ __launch_bounds__(256) void k_bookf(const float* __restrict__ book,
                                               u16* __restrict__ bookF)
{
  const int tid = blockIdx.x*256 + threadIdx.x;   // (jc*16+dt)*64+lane
  const int l  = tid & 63;
  const int dt = (tid >> 6) & 15;
  const int jc = tid >> 10;
  const int d  = dt*16 + (l & 15);
  const int jb = jc*32 + (l >> 4)*8;
  u16x8 v;
  #pragma unroll
  for (int e = 0; e < 8; ++e) v[e] = f2bf(book[(size_t)(jb + e)*DIM + d]);
  *(u16x8*)&bookF[(size_t)tid*8] = v;
}

// ---------------- K1: mu_mix, zp (into zq slot), row norms ------------------
// Barrier-free main loop: lane owns 4 dims (float4), wave owns a row.
// grid (NPTS, 2): each block does 32 b's (8 per wave).
__global__ __launch_bounds__(256) void k_mix(const float* __restrict__ z,
    const float* __restrict__ cp, const float* __restrict__ mu,
    float* __restrict__ zp, float* __restrict__ mm, float* __restrict__ rn)
{
  __shared__ float s_cp[BB*NC];   // 1024
  const int n  = blockIdx.x;
  const int t  = threadIdx.x;
  const int wv = t >> 6, ln = t & 63;
  for (int e = t; e < BB*NC; e += 256) s_cp[e] = cp[e];
  const int d0 = ln*4;
  float4 muv[NC];
  #pragma unroll
  for (int c = 0; c < NC; ++c)
    muv[c] = *(const float4*)&mu[(size_t)(c*NPTS + n)*DIM + d0];
  __syncthreads();
  const int b0 = blockIdx.y*32 + wv*8;
  #pragma unroll 2
  for (int bb = 0; bb < 8; ++bb){
    const int b = b0 + bb;
    const size_t idx = ((size_t)(b*NPTS + n))*DIM + d0;
    const float4 z4 = *(const float4*)&z[idx];
    float4 m4 = {0.f, 0.f, 0.f, 0.f};
    #pragma unroll
    for (int c = 0; c < NC; ++c){
      const float wgt = s_cp[b*NC + c];
      m4.x = fmaf(wgt, muv[c].x, m4.x);
      m4.y = fmaf(wgt, muv[c].y, m4.y);
      m4.z = fmaf(wgt, muv[c].z, m4.z);
      m4.w = fmaf(wgt, muv[c].w, m4.w);
    }
    float4 zp4;
    zp4.x = z4.x + m4.x; zp4.y = z4.y + m4.y;
    zp4.z = z4.z + m4.z; zp4.w = z4.w + m4.w;
    *(float4*)&mm[idx] = m4;
    *(float4*)&zp[idx] = zp4;
    float s = zp4.x*zp4.x + zp4.y*zp4.y + zp4.z*zp4.z + zp4.w*zp4.w;
    #pragma unroll
    for (int o = 32; o; o >>= 1) s += __shfl_down(s, o, 64);
    if (ln == 0) rn[b*NPTS + n] = s;
  }
}

// ---------------- K2: logits GEMM via bf16 MFMA (+ optional fused row-max) --
// 128x128 tile, 4 waves 2x2, each wave 64x64 (4x4 tiles of 16x16), K chunks of 64.
// LDS row pitch 72 bf16 = 144 B. Row-max accumulated via mapped atomicMax.
__global__ __launch_bounds__(256) void k_logits(const float* __restrict__ zp,
    const float* __restrict__ book, const float* __restrict__ rn,
    const float* __restrict__ bn, const float* __restrict__ ws_pq,
    float* __restrict__ logits, unsigned int* __restrict__ wsMax)
{
  __shared__ u16 sA[128*72];
  __shared__ u16 sB[128*72];
  const int t  = threadIdx.x;
  const int l  = t & 63;
  const int w  = t >> 6;
  const int i0 = blockIdx.y * 128;
  const int j0 = blockIdx.x * 128;
  const int wr = (w >> 1) * 64;
  const int wc = (w & 1) * 64;
  const int ll = l & 15, lh = l >> 4;

  f32x4 acc[4][4];
  #pragma unroll
  for (int m = 0; m < 4; ++m)
    #pragma unroll
    for (int n = 0; n < 4; ++n)
      acc[m][n] = (f32x4){0.f, 0.f, 0.f, 0.f};

  for (int k0 = 0; k0 < DIM; k0 += 64){
    #pragma unroll
    for (int e = 0; e < 8; ++e){
      const int idx = e*256 + t;
      const int r  = idx >> 4;
      const int dd = (idx & 15) * 4;
      const float4 a4 = *(const float4*)&zp[(size_t)(i0 + r)*DIM + k0 + dd];
      const float4 b4 = *(const float4*)&book[(size_t)(j0 + r)*DIM + k0 + dd];
      u16x4 av, bv;
      av[0] = f2bf(a4.x); av[1] = f2bf(a4.y); av[2] = f2bf(a4.z); av[3] = f2bf(a4.w);
      bv[0] = f2bf(b4.x); bv[1] = f2bf(b4.y); bv[2] = f2bf(b4.z); bv[3] = f2bf(b4.w);
      *(u16x4*)&sA[r*72 + dd] = av;
      *(u16x4*)&sB[r*72 + dd] = bv;
    }
    __syncthreads();
    #pragma unroll
    for (int kk = 0; kk < 2; ++kk){
      s8v aF[4], bF[4];
      #pragma unroll
      for (int m = 0; m < 4; ++m)
        aF[m] = *(const s8v*)&sA[(wr + m*16 + ll)*72 + kk*32 + lh*8];
      #pragma unroll
      for (int n = 0; n < 4; ++n)
        bF[n] = *(const s8v*)&sB[(wc + n*16 + ll)*72 + kk*32 + lh*8];
      #pragma unroll
      for (int m = 0; m < 4; ++m)
        #pragma unroll
        for (int n = 0; n < 4; ++n)
          acc[m][n] = __builtin_amdgcn_mfma_f32_16x16x32_bf16(aF[m], bF[n], acc[m][n], 0, 0, 0);
    }
    __syncthreads();
  }

  // epilogue: C/D layout col = lane&15, row = (lane>>4)*4 + reg
  const float pq = ws_pq[0];
  float bnv[4];
  #pragma unroll
  for (int n = 0; n < 4; ++n) bnv[n] = bn[j0 + wc + n*16 + ll];
  #pragma unroll
  for (int m = 0; m < 4; ++m){
    #pragma unroll
    for (int r = 0; r < 4; ++r){
      const int i = i0 + wr + m*16 + lh*4 + r;
      const float rni = rn[i];
      const size_t base = (size_t)i*BOOKN + j0 + wc + ll;
      float vmax = -3.4e38f;
      #pragma unroll
      for (int n = 0; n < 4; ++n){
        const float val = -pq * (rni + bnv[n] - 2.0f*acc[m][n][r]);
        logits[base + n*16] = val;
        vmax = fmaxf(vmax, val);
      }
      if (wsMax != nullptr){   // wave-uniform branch
        #pragma unroll
        for (int o = 1; o < 16; o <<= 1)
          vmax = fmaxf(vmax, __shfl_xor(vmax, o, 64));
        if (ll == 0) atomicMax(&wsMax[i], mf_map(vmax));
      }
    }
  }
}

// ---------------- K3: fused gumbel-softmax + zq GEMM via bf16 MFMA ----------
// gumbel folded: p = exp2( ((l-m)*log2e - ln2*log2e*log2(w)) / T ),
// w = eps - ln(u+eps) = fma(-ln2, log2(u+eps), eps)
// => two v_log_f32 + one v_exp_f32 per element (vs 2 libm logf + 1 libm expf).
// Row max from wsMax if present (fused in k_logits); else in-kernel pre-pass.
__global__ __launch_bounds__(256) void k_zq(const float* __restrict__ logits,
    const u16* __restrict__ bookF, const int* __restrict__ temp,
    const unsigned int* __restrict__ wsMax, float* __restrict__ zq)
{
  __shared__ u16 sP[64*40];
  __shared__ float sM[64];
  __shared__ float sS[64][8];
  __shared__ float sInv[64];
  const int t  = threadIdx.x;
  const int i0 = blockIdx.x * 32;
  const float tinv = 1.0f / (float)temp[0];
  const float sc = tinv * 1.44269504f;   // log2(e)/T

  if (wsMax != nullptr){
    if (t < 64){
      const int gi = (t < 32) ? (i0 + t) : (i0 + t - 32 + HALF_ROWS);
      sM[t] = mf_unmap(wsMax[gi]) + 17.0f;   // +17 covers max gumbel (~16.64)
    }
  } else {
    // fallback: per-row max of logits (round-1-proven path)
    const int wv = t >> 6, ln = t & 63;
    for (int rr = 0; rr < 16; ++rr){
      const int r = wv*16 + rr;
      const int gi = (r < 32) ? (i0 + r) : (i0 + r - 32 + HALF_ROWS);
      const float* row = logits + (size_t)gi*BOOKN;
      float mx = -3.4e38f;
      #pragma unroll 4
      for (int e = 0; e < 32; ++e) mx = fmaxf(mx, row[e*64 + ln]);
      #pragma unroll
      for (int o = 32; o; o >>= 1) mx = fmaxf(mx, __shfl_down(mx, o, 64));
      if (ln == 0) sM[r] = mx + 17.0f;
    }
  }
  __syncthreads();

  const int w   = t >> 6;        // wave id: owns d-range w*64 .. +63
  const int l   = t & 63;
  const int ll  = l & 15, lh = l >> 4;
  const int srA = t >> 3;        // staging row 0..31
  const int sj0 = (t & 7) * 4;   // staging col start within chunk
  const int giA = i0 + srA;
  const float mA = sM[srA];
  const float mB = sM[srA + 32];
  const float* rowA = logits + (size_t)giA*BOOKN;
  const float* rowB = logits + (size_t)(giA + HALF_ROWS)*BOOKN;

  f32x4 acc[4][4];
  #pragma unroll
  for (int m = 0; m < 4; ++m)
    #pragma unroll
    for (int n = 0; n < 4; ++n)
      acc[m][n] = (f32x4){0.f, 0.f, 0.f, 0.f};
  float sumA = 0.f, sumB = 0.f;

  for (int jc = 0; jc < 64; ++jc){
    const int jbase = jc*32 + sj0;
    const float4 lA4 = *(const float4*)(rowA + jbase);
    const float4 lB4 = *(const float4*)(rowB + jbase);
    const float la[4] = {lA4.x, lA4.y, lA4.z, lA4.w};
    const float lb[4] = {lB4.x, lB4.y, lB4.z, lB4.w};
    #pragma unroll
    for (int e = 0; e < 4; ++e){
      const uint32_t p = (uint32_t)(giA*BOOKN + jbase + e);   // < HALF_N
      uint32_t o0, o1;
      threefry_0_42(p, p + HALF_N, o0, o1);
      const float uA = __uint_as_float((o0 >> 9) | 0x3f800000u) - 1.0f;
      const float uB = __uint_as_float((o1 >> 9) | 0x3f800000u) - 1.0f;
      const float wAv = fmaf(-0.69314718f, FAST_LOG2(uA + 1e-10f), 1e-10f);
      const float wBv = fmaf(-0.69314718f, FAST_LOG2(uB + 1e-10f), 1e-10f);
      const float eAv = ((la[e] - mA) - 0.69314718f*FAST_LOG2(wAv)) * sc;
      const float eBv = ((lb[e] - mB) - 0.69314718f*FAST_LOG2(wBv)) * sc;
      const u16 pa = f2bf(FAST_EXP2(eAv));
      const u16 pb = f2bf(FAST_EXP2(eBv));
      sP[srA*40 + sj0 + e]        = pa;
      sP[(srA + 32)*40 + sj0 + e] = pb;
      sumA += bf2f(pa);
      sumB += bf2f(pb);
    }
    // B frags: coalesced 16B/lane from L2-resident bookF (independent of sP)
    s8v bF[4];
    #pragma unroll
    for (int n = 0; n < 4; ++n)
      bF[n] = *(const s8v*)&bookF[((size_t)(jc*16 + w*4 + n)*64 + l)*8];
    __syncthreads();
    s8v aF[4];
    #pragma unroll
    for (int m = 0; m < 4; ++m)
      aF[m] = *(const s8v*)&sP[(m*16 + ll)*40 + lh*8];
    #pragma unroll
    for (int n = 0; n < 4; ++n)
      #pragma unroll
      for (int m = 0; m < 4; ++m)
        acc[m][n] = __builtin_amdgcn_mfma_f32_16x16x32_bf16(aF[m], bF[n], acc[m][n], 0, 0, 0);
    __syncthreads();
  }

  // S reduction (8 partials per row)
  sS[srA][t & 7]      = sumA;
  sS[srA + 32][t & 7] = sumB;
  __syncthreads();
  if (t < 64){
    float s = 0.f;
    #pragma unroll
    for (int e = 0; e < 8; ++e) s += sS[t][e];
    sInv[t] = 1.0f / s;
  }
  __syncthreads();

  // epilogue: zq = acc / S.  C/D: col(d) = lane&15, row = (lane>>4)*4 + reg
  #pragma unroll
  for (int m = 0; m < 4; ++m){
    #pragma unroll
    for (int r = 0; r < 4; ++r){
      const int lr = m*16 + lh*4 + r;
      const int gi = (lr < 32) ? (i0 + lr) : (i0 + lr - 32 + HALF_ROWS);
      const float inv = sInv[lr];
      #pragma unroll
      for (int n = 0; n < 4; ++n)
        zq[(size_t)gi*DIM + w*64 + n*16 + ll] = acc[m][n][r] * inv;
    }
  }
}

// ---------------- launch ----------------------------------------------------
extern "C" void kernel_launch(void* const* d_in, const int* in_sizes, int n_in,
                              void* d_out, int out_size, void* d_ws, size_t ws_size,
                              hipStream_t stream)
{
  (void)in_sizes; (void)n_in; (void)out_size;
  const float* z    = (const float*)d_in[0];
  const float* cp   = (const float*)d_in[1];
  const float* lpq  = (const float*)d_in[2];
  const float* book = (const float*)d_in[3];
  const float* mu   = (const float*)d_in[4];
  const int*   temp = (const int*)d_in[5];
  // d_in[6] = is_train, unused by the reference computation

  float* out = (float*)d_out;
  float* zq  = out;             // also used as zp scratch between K1 and K2
  float* pqo = out + OFF_PQ;
  float* lg  = out + OFF_LG;
  float* mm  = out + OFF_MM;

  float* ws    = (float*)d_ws;  // proven >= 1.32 MB; fused rowmax needs 1.59 MB
  float* bn    = ws;
  float* rn    = ws + WS_RN;
  float* wpq   = ws + WS_PQ;
  u16*   bookF = (u16*)(ws + WS_BF);
  unsigned int* wsMax = (ws_size >= WS_FUSED_BYTES)
                      ? (unsigned int*)(ws + WS_MX) : nullptr;

  hipLaunchKernelGGL(k_prep,   dim3(BOOKN), dim3(256), 0, stream,
                     book, lpq, bn, wpq, pqo, wsMax);
  hipLaunchKernelGGL(k_bookf,  dim3(256), dim3(256), 0, stream,
                     book, bookF);
  hipLaunchKernelGGL(k_mix,    dim3(NPTS, 2), dim3(256), 0, stream,
                     z, cp, mu, zq, mm, rn);
  hipLaunchKernelGGL(k_logits, dim3(BOOKN/128, NROWS/128), dim3(256), 0, stream,
                     zq, book, rn, bn, wpq, lg, wsMax);
  hipLaunchKernelGGL(k_zq,     dim3(HALF_ROWS/32), dim3(256), 0, stream,
                     lg, bookF, temp, wsMax, zq);
}

// Round 5
// 1222.580 us; speedup vs baseline: 2.3505x; 1.0563x over previous
//
#include <hip/hip_runtime.h>
#include <stdint.h>

// Problem constants
#define BB     64
#define NPTS   1024
#define DIM    256
#define BOOKN  2048
#define NC     16
#define NROWS  (BB*NPTS)           // 65536
#define HALF_N 67108864u           // NROWS*BOOKN/2
#define HALF_ROWS 32768            // NROWS/2

// d_out layout (floats): [zq | precision_q | logits | mu_mix]
#define OFF_PQ ((size_t)NROWS*DIM)            // 16777216
#define OFF_LG (OFF_PQ + 1)                   // 16777217
#define OFF_MM (OFF_LG + (size_t)NROWS*BOOKN) // 150994945

// ws layout (floats): bn[2048], rn[65536], pq[1], pad, bookF(1MB as bf16),
// then OPTIONAL rowmax(65536 u32) if ws_size permits.
#define WS_RN 2048
#define WS_PQ (2048 + NROWS)
#define WS_BF 67592                            // float offset, 16B aligned
#define WS_MX (WS_BF + (BOOKN*DIM)/2)          // 329736 (float offset)
#define WS_FUSED_BYTES ((size_t)(WS_MX + NROWS) * 4)   // 1,581,088

// fast hardware transcendentals (v_log_f32 = log2, v_exp_f32 = exp2), with
// guaranteed-compile libm fallback. NOTE: __log2f/__exp2f collide with glibc
// math.h internal decls — do not use those names.
#if defined(__has_builtin)
# if __has_builtin(__builtin_amdgcn_logf)
#  define FAST_LOG2(x) __builtin_amdgcn_logf(x)
# endif
# if __has_builtin(__builtin_amdgcn_exp2f)
#  define FAST_EXP2(x) __builtin_amdgcn_exp2f(x)
# endif
#endif
#ifndef FAST_LOG2
# define FAST_LOG2(x) log2f(x)
#endif
#ifndef FAST_EXP2
# define FAST_EXP2(x) exp2f(x)
#endif

typedef unsigned short u16;
typedef short s8v  __attribute__((ext_vector_type(8)));   // 8 bf16 = 4 VGPR (MFMA A/B frag)
typedef float f32x4 __attribute__((ext_vector_type(4)));  // MFMA C/D frag
typedef u16  u16x4 __attribute__((ext_vector_type(4)));
typedef u16  u16x8 __attribute__((ext_vector_type(8)));

__device__ __forceinline__ u16 f2bf(float x){
  uint32_t u = __float_as_uint(x);
  return (u16)((u + 0x7fffu + ((u >> 16) & 1u)) >> 16);   // RNE
}
__device__ __forceinline__ float bf2f(u16 b){
  return __uint_as_float(((uint32_t)b) << 16);
}

// monotone float<->uint map (uint compare == float compare), for atomicMax
__device__ __forceinline__ uint32_t mf_map(float f){
  uint32_t b = __float_as_uint(f);
  return (b & 0x80000000u) ? ~b : (b | 0x80000000u);
}
__device__ __forceinline__ float mf_unmap(uint32_t u){
  uint32_t b = (u & 0x80000000u) ? (u ^ 0x80000000u) : ~u;
  return __uint_as_float(b);
}

// ---------------- threefry2x32-20, JAX semantics, key = (0, 42) -------------
__device__ __forceinline__ uint32_t rotl32(uint32_t x, int r){
  return (x << r) | (x >> (32 - r));
}

__device__ __forceinline__ void threefry_0_42(uint32_t x0, uint32_t x1,
                                              uint32_t& o0, uint32_t& o1){
  const uint32_t ks0 = 0u;
  const uint32_t ks1 = 42u;
  const uint32_t ks2 = 0u ^ 42u ^ 0x1BD11BDAu;
  x0 += ks0; x1 += ks1;
#define TF_R(r) { x0 += x1; x1 = rotl32(x1, r); x1 ^= x0; }
  TF_R(13) TF_R(15) TF_R(26) TF_R(6)
  x0 += ks1; x1 += ks2 + 1u;
  TF_R(17) TF_R(29) TF_R(16) TF_R(24)
  x0 += ks2; x1 += ks0 + 2u;
  TF_R(13) TF_R(15) TF_R(26) TF_R(6)
  x0 += ks0; x1 += ks1 + 3u;
  TF_R(17) TF_R(29) TF_R(16) TF_R(24)
  x0 += ks1; x1 += ks2 + 4u;
  TF_R(13) TF_R(15) TF_R(26) TF_R(6)
  x0 += ks2; x1 += ks0 + 5u;
#undef TF_R
  o0 = x0; o1 = x1;
}

// ---------------- K0: book norms + precision_q + rowmax init ----------------
__global__ __launch_bounds__(256) void k_prep(const float* __restrict__ book,
    const float* __restrict__ lpq, float* __restrict__ bn,
    float* __restrict__ ws_pq, float* __restrict__ pq_out,
    unsigned int* __restrict__ wsMax)
{
  __shared__ float red[4];
  const int j = blockIdx.x, t = threadIdx.x;
  const int gid = j*256 + t;
  if (wsMax != nullptr && gid < NROWS) wsMax[gid] = 0u;  // maps below any finite float
  float v = book[(size_t)j*DIM + t];
  float s = v*v;
  #pragma unroll
  for (int o = 32; o; o >>= 1) s += __shfl_down(s, o, 64);
  const int wv = t >> 6, ln = t & 63;
  if (ln == 0) red[wv] = s;
  __syncthreads();
  if (t == 0){
    bn[j] = red[0] + red[1] + red[2] + red[3];
    if (j == 0){
      float pq = fmaxf(expf(lpq[0]), 1e-10f);
      float prec = 0.5f / pq;
      ws_pq[0] = prec;
      pq_out[0] = prec;
    }
  }
}

// ---------------- K0b: bf16 book in two layouts -----------------------------
// bookF (frag order for k_zq): element e = book[jc*32 + (lane>>4)*8 + e][dt*16 + (lane&15)]
// bookR (row-major bf16 for k_logits staging)
__global__ __launch_bounds__(256) void k_bookf(const float* __restrict__ book,
                                               u16* __restrict__ bookF,
                                               u16* __restrict__ bookR)
{
  const int tid = blockIdx.x*256 + threadIdx.x;   // 0..65535
  {
    const int l  = tid & 63;
    const int dt = (tid >> 6) & 15;
    const int jc = tid >> 10;
    const int d  = dt*16 + (l & 15);
    const int jb = jc*32 + (l >> 4)*8;
    u16x8 v;
    #pragma unroll
    for (int e = 0; e < 8; ++e) v[e] = f2bf(book[(size_t)(jb + e)*DIM + d]);
    *(u16x8*)&bookF[(size_t)tid*8] = v;
  }
  {
    const int rr = tid >> 5;          // 0..2047
    const int cc = (tid & 31) * 8;    // 0..248
    const float4 f0 = *(const float4*)&book[(size_t)rr*DIM + cc];
    const float4 f1 = *(const float4*)&book[(size_t)rr*DIM + cc + 4];
    u16x8 wv;
    wv[0] = f2bf(f0.x); wv[1] = f2bf(f0.y); wv[2] = f2bf(f0.z); wv[3] = f2bf(f0.w);
    wv[4] = f2bf(f1.x); wv[5] = f2bf(f1.y); wv[6] = f2bf(f1.z); wv[7] = f2bf(f1.w);
    *(u16x8*)&bookR[(size_t)rr*DIM + cc] = wv;
  }
}

// ---------------- K1: mu_mix, zp (as bf16, into zq slot), row norms ---------
// Barrier-free main loop: lane owns 4 dims (float4), wave owns a row.
// grid (NPTS, 2): each block does 32 b's (8 per wave).
// zp is stored as bf16 (identical rounding to what k_logits did before).
__global__ __launch_bounds__(256) void k_mix(const float* __restrict__ z,
    const float* __restrict__ cp, const float* __restrict__ mu,
    u16* __restrict__ zpBF, float* __restrict__ mm, float* __restrict__ rn)
{
  __shared__ float s_cp[BB*NC];   // 1024
  const int n  = blockIdx.x;
  const int t  = threadIdx.x;
  const int wv = t >> 6, ln = t & 63;
  for (int e = t; e < BB*NC; e += 256) s_cp[e] = cp[e];
  const int d0 = ln*4;
  float4 muv[NC];
  #pragma unroll
  for (int c = 0; c < NC; ++c)
    muv[c] = *(const float4*)&mu[(size_t)(c*NPTS + n)*DIM + d0];
  __syncthreads();
  const int b0 = blockIdx.y*32 + wv*8;
  #pragma unroll 2
  for (int bb = 0; bb < 8; ++bb){
    const int b = b0 + bb;
    const size_t idx = ((size_t)(b*NPTS + n))*DIM + d0;
    const float4 z4 = *(const float4*)&z[idx];
    float4 m4 = {0.f, 0.f, 0.f, 0.f};
    #pragma unroll
    for (int c = 0; c < NC; ++c){
      const float wgt = s_cp[b*NC + c];
      m4.x = fmaf(wgt, muv[c].x, m4.x);
      m4.y = fmaf(wgt, muv[c].y, m4.y);
      m4.z = fmaf(wgt, muv[c].z, m4.z);
      m4.w = fmaf(wgt, muv[c].w, m4.w);
    }
    float4 zp4;
    zp4.x = z4.x + m4.x; zp4.y = z4.y + m4.y;
    zp4.z = z4.z + m4.z; zp4.w = z4.w + m4.w;
    *(float4*)&mm[idx] = m4;
    u16x4 zb;
    zb[0] = f2bf(zp4.x); zb[1] = f2bf(zp4.y);
    zb[2] = f2bf(zp4.z); zb[3] = f2bf(zp4.w);
    *(u16x4*)&zpBF[idx] = zb;
    float s = zp4.x*zp4.x + zp4.y*zp4.y + zp4.z*zp4.z + zp4.w*zp4.w;
    #pragma unroll
    for (int o = 32; o; o >>= 1) s += __shfl_down(s, o, 64);
    if (ln == 0) rn[b*NPTS + n] = s;
  }
}

// ---------------- K2: logits GEMM via bf16 MFMA (+ optional fused row-max) --
// 128x128 tile, 4 waves 2x2, each wave 64x64 (4x4 tiles of 16x16), K chunks of 64.
// Inputs are pre-converted bf16 (zpBF, bookR): staging = pure 16B copies, no cvt.
// LDS row pitch 72 bf16 = 144 B. Row-max accumulated via mapped atomicMax.
__global__ __launch_bounds__(256) void k_logits(const u16* __restrict__ zpBF,
    const u16* __restrict__ bookR, const float* __restrict__ rn,
    const float* __restrict__ bn, const float* __restrict__ ws_pq,
    float* __restrict__ logits, unsigned int* __restrict__ wsMax)
{
  __shared__ u16 sA[128*72];
  __shared__ u16 sB[128*72];
  const int t  = threadIdx.x;
  const int l  = t & 63;
  const int w  = t >> 6;
  const int i0 = blockIdx.y * 128;
  const int j0 = blockIdx.x * 128;
  const int wr = (w >> 1) * 64;
  const int wc = (w & 1) * 64;
  const int ll = l & 15, lh = l >> 4;

  f32x4 acc[4][4];
  #pragma unroll
  for (int m = 0; m < 4; ++m)
    #pragma unroll
    for (int n = 0; n < 4; ++n)
      acc[m][n] = (f32x4){0.f, 0.f, 0.f, 0.f};

  for (int k0 = 0; k0 < DIM; k0 += 64){
    #pragma unroll
    for (int e = 0; e < 4; ++e){
      const int idx = e*256 + t;        // 0..1023
      const int r   = idx >> 3;         // 0..127
      const int c8  = (idx & 7) * 8;    // 0..56
      *(u16x8*)&sA[r*72 + c8] =
          *(const u16x8*)&zpBF[(size_t)(i0 + r)*DIM + k0 + c8];
      *(u16x8*)&sB[r*72 + c8] =
          *(const u16x8*)&bookR[(size_t)(j0 + r)*DIM + k0 + c8];
    }
    __syncthreads();
    #pragma unroll
    for (int kk = 0; kk < 2; ++kk){
      s8v aF[4], bF[4];
      #pragma unroll
      for (int m = 0; m < 4; ++m)
        aF[m] = *(const s8v*)&sA[(wr + m*16 + ll)*72 + kk*32 + lh*8];
      #pragma unroll
      for (int n = 0; n < 4; ++n)
        bF[n] = *(const s8v*)&sB[(wc + n*16 + ll)*72 + kk*32 + lh*8];
      #pragma unroll
      for (int m = 0; m < 4; ++m)
        #pragma unroll
        for (int n = 0; n < 4; ++n)
          acc[m][n] = __builtin_amdgcn_mfma_f32_16x16x32_bf16(aF[m], bF[n], acc[m][n], 0, 0, 0);
    }
    __syncthreads();
  }

  // epilogue: C/D layout col = lane&15, row = (lane>>4)*4 + reg
  const float pq = ws_pq[0];
  float bnv[4];
  #pragma unroll
  for (int n = 0; n < 4; ++n) bnv[n] = bn[j0 + wc + n*16 + ll];
  #pragma unroll
  for (int m = 0; m < 4; ++m){
    #pragma unroll
    for (int r = 0; r < 4; ++r){
      const int i = i0 + wr + m*16 + lh*4 + r;
      const float rni = rn[i];
      const size_t base = (size_t)i*BOOKN + j0 + wc + ll;
      float vmax = -3.4e38f;
      #pragma unroll
      for (int n = 0; n < 4; ++n){
        const float val = -pq * (rni + bnv[n] - 2.0f*acc[m][n][r]);
        logits[base + n*16] = val;
        vmax = fmaxf(vmax, val);
      }
      if (wsMax != nullptr){   // wave-uniform branch
        #pragma unroll
        for (int o = 1; o < 16; o <<= 1)
          vmax = fmaxf(vmax, __shfl_xor(vmax, o, 64));
        if (ll == 0) atomicMax(&wsMax[i], mf_map(vmax));
      }
    }
  }
}

// ---------------- K3: fused gumbel-softmax + zq GEMM via bf16 MFMA ----------
// gumbel folded: p = exp2( ((l-m) - ln2*log2(w)) * (log2e/T) ),
// w = eps - ln(u+eps) = fma(-ln2, log2(u+eps), eps)
// => two v_log_f32 + one v_exp_f32 per element.
// Row max from wsMax if present (fused in k_logits); else in-kernel pre-pass.
__global__ __launch_bounds__(256) void k_zq(const float* __restrict__ logits,
    const u16* __restrict__ bookF, const int* __restrict__ temp,
    const unsigned int* __restrict__ wsMax, float* __restrict__ zq)
{
  __shared__ u16 sP[64*40];
  __shared__ float sM[64];
  __shared__ float sS[64][8];
  __shared__ float sInv[64];
  const int t  = threadIdx.x;
  const int i0 = blockIdx.x * 32;
  const float tinv = 1.0f / (float)temp[0];
  const float sc = tinv * 1.44269504f;   // log2(e)/T

  if (wsMax != nullptr){
    if (t < 64){
      const int gi = (t < 32) ? (i0 + t) : (i0 + t - 32 + HALF_ROWS);
      sM[t] = mf_unmap(wsMax[gi]) + 17.0f;   // +17 covers max gumbel (~16.64)
    }
  } else {
    // fallback: per-row max of logits (round-1-proven path)
    const int wv = t >> 6, ln = t & 63;
    for (int rr = 0; rr < 16; ++rr){
      const int r = wv*16 + rr;
      const int gi = (r < 32) ? (i0 + r) : (i0 + r - 32 + HALF_ROWS);
      const float* row = logits + (size_t)gi*BOOKN;
      float mx = -3.4e38f;
      #pragma unroll 4
      for (int e = 0; e < 32; ++e) mx = fmaxf(mx, row[e*64 + ln]);
      #pragma unroll
      for (int o = 32; o; o >>= 1) mx = fmaxf(mx, __shfl_down(mx, o, 64));
      if (ln == 0) sM[r] = mx + 17.0f;
    }
  }
  __syncthreads();

  const int w   = t >> 6;        // wave id: owns d-range w*64 .. +63
  const int l   = t & 63;
  const int ll  = l & 15, lh = l >> 4;
  const int srA = t >> 3;        // staging row 0..31
  const int sj0 = (t & 7) * 4;   // staging col start within chunk
  const int giA = i0 + srA;
  const float mA = sM[srA];
  const float mB = sM[srA + 32];
  const float* rowA = logits + (size_t)giA*BOOKN;
  const float* rowB = logits + (size_t)(giA + HALF_ROWS)*BOOKN;

  f32x4 acc[4][4];
  #pragma unroll
  for (int m = 0; m < 4; ++m)
    #pragma unroll
    for (int n = 0; n < 4; ++n)
      acc[m][n] = (f32x4){0.f, 0.f, 0.f, 0.f};
  float sumA = 0.f, sumB = 0.f;

  for (int jc = 0; jc < 64; ++jc){
    const int jbase = jc*32 + sj0;
    const float4 lA4 = *(const float4*)(rowA + jbase);
    const float4 lB4 = *(const float4*)(rowB + jbase);
    const float la[4] = {lA4.x, lA4.y, lA4.z, lA4.w};
    const float lb[4] = {lB4.x, lB4.y, lB4.z, lB4.w};
    #pragma unroll
    for (int e = 0; e < 4; ++e){
      const uint32_t p = (uint32_t)(giA*BOOKN + jbase + e);   // < HALF_N
      uint32_t o0, o1;
      threefry_0_42(p, p + HALF_N, o0, o1);
      const float uA = __uint_as_float((o0 >> 9) | 0x3f800000u) - 1.0f;
      const float uB = __uint_as_float((o1 >> 9) | 0x3f800000u) - 1.0f;
      const float wAv = fmaf(-0.69314718f, FAST_LOG2(uA + 1e-10f), 1e-10f);
      const float wBv = fmaf(-0.69314718f, FAST_LOG2(uB + 1e-10f), 1e-10f);
      const float eAv = ((la[e] - mA) - 0.69314718f*FAST_LOG2(wAv)) * sc;
      const float eBv = ((lb[e] - mB) - 0.69314718f*FAST_LOG2(wBv)) * sc;
      const u16 pa = f2bf(FAST_EXP2(eAv));
      const u16 pb = f2bf(FAST_EXP2(eBv));
      sP[srA*40 + sj0 + e]        = pa;
      sP[(srA + 32)*40 + sj0 + e] = pb;
      sumA += bf2f(pa);
      sumB += bf2f(pb);
    }
    // B frags: coalesced 16B/lane from L2-resident bookF (independent of sP)
    s8v bF[4];
    #pragma unroll
    for (int n = 0; n < 4; ++n)
      bF[n] = *(const s8v*)&bookF[((size_t)(jc*16 + w*4 + n)*64 + l)*8];
    __syncthreads();
    s8v aF[4];
    #pragma unroll
    for (int m = 0; m < 4; ++m)
      aF[m] = *(const s8v*)&sP[(m*16 + ll)*40 + lh*8];
    #pragma unroll
    for (int n = 0; n < 4; ++n)
      #pragma unroll
      for (int m = 0; m < 4; ++m)
        acc[m][n] = __builtin_amdgcn_mfma_f32_16x16x32_bf16(aF[m], bF[n], acc[m][n], 0, 0, 0);
    __syncthreads();
  }

  // S reduction (8 partials per row)
  sS[srA][t & 7]      = sumA;
  sS[srA + 32][t & 7] = sumB;
  __syncthreads();
  if (t < 64){
    float s = 0.f;
    #pragma unroll
    for (int e = 0; e < 8; ++e) s += sS[t][e];
    sInv[t] = 1.0f / s;
  }
  __syncthreads();

  // epilogue: zq = acc / S.  C/D: col(d) = lane&15, row = (lane>>4)*4 + reg
  #pragma unroll
  for (int m = 0; m < 4; ++m){
    #pragma unroll
    for (int r = 0; r < 4; ++r){
      const int lr = m*16 + lh*4 + r;
      const int gi = (lr < 32) ? (i0 + lr) : (i0 + lr - 32 + HALF_ROWS);
      const float inv = sInv[lr];
      #pragma unroll
      for (int n = 0; n < 4; ++n)
        zq[(size_t)gi*DIM + w*64 + n*16 + ll] = acc[m][n][r] * inv;
    }
  }
}

// ---------------- launch ----------------------------------------------------
extern "C" void kernel_launch(void* const* d_in, const int* in_sizes, int n_in,
                              void* d_out, int out_size, void* d_ws, size_t ws_size,
                              hipStream_t stream)
{
  (void)in_sizes; (void)n_in; (void)out_size;
  const float* z    = (const float*)d_in[0];
  const float* cp   = (const float*)d_in[1];
  const float* lpq  = (const float*)d_in[2];
  const float* book = (const float*)d_in[3];
  const float* mu   = (const float*)d_in[4];
  const int*   temp = (const int*)d_in[5];
  // d_in[6] = is_train, unused by the reference computation

  float* out = (float*)d_out;
  float* zq  = out;             // scratch between K1 and K2, final zq after K3
  float* pqo = out + OFF_PQ;
  float* lg  = out + OFF_LG;
  float* mm  = out + OFF_MM;

  // scratch carved from the zq region (dead by the time k_zq writes it):
  // zpBF  = bf16 zp, 32 MB, first half
  // bookR = bf16 row-major book, 1 MB, at the +32 MB mark
  u16* zpBF  = (u16*)zq;
  u16* bookR = (u16*)zq + (size_t)NROWS*DIM;

  float* ws    = (float*)d_ws;  // proven >= 1.32 MB; fused rowmax needs 1.59 MB
  float* bn    = ws;
  float* rn    = ws + WS_RN;
  float* wpq   = ws + WS_PQ;
  u16*   bookF = (u16*)(ws + WS_BF);
  unsigned int* wsMax = (ws_size >= WS_FUSED_BYTES)
                      ? (unsigned int*)(ws + WS_MX) : nullptr;

  hipLaunchKernelGGL(k_prep,   dim3(BOOKN), dim3(256), 0, stream,
                     book, lpq, bn, wpq, pqo, wsMax);
  hipLaunchKernelGGL(k_bookf,  dim3(256), dim3(256), 0, stream,
                     book, bookF, bookR);
  hipLaunchKernelGGL(k_mix,    dim3(NPTS, 2), dim3(256), 0, stream,
                     z, cp, mu, zpBF, mm, rn);
  hipLaunchKernelGGL(k_logits, dim3(BOOKN/128, NROWS/128), dim3(256), 0, stream,
                     zpBF, bookR, rn, bn, wpq, lg, wsMax);
  hipLaunchKernelGGL(k_zq,     dim3(HALF_ROWS/32), dim3(256), 0, stream,
                     lg, bookF, temp, wsMax, zq);
}